// Round 3
// baseline (415.737 us; speedup 1.0000x reference)
//
#include <hip/hip_runtime.h>

// R3: transposed-orientation fused MLP (R2 design, compile fix: manual bf16
// pair packing instead of __builtin_bit_cast on __hip_bfloat162).
// Every layer computes H^T = W * Hprev^T (A = weight frags, B = activation
// frags). Neuron-permutation sigma folded into weight staging so inter-layer
// C-layout -> B-layout is a pure in-lane register repack (no LDS, no shuffles).
//
//  - W2/W3 A-frags (64 KB bf16) in LDS, ds_read_b128 per use, amortized over
//    T=4 row-tiles (64 rows) per wave-iteration.
//  - L1/L4 frags + bias tables pre-staged to d_ws by nerf_stage, read from L2.
//  - Biases enter as the MFMA C operand at ks==0 (exact fp32 add, no movs).
//  - launch_bounds(256,2): 2 blocks/CU, 8 waves/CU -> MFMA/VALU co-issue.
//
// ws layout (bytes):
//   0      : 76 A-frags, 1024 B each (frag f: lane l holds short8 at f*1024+l*16)
//            f 0..7 = L1 (nt) | f 8..39 = L2 (ks*8+nt) | f 40..71 = L3 | f 72..75 = L4 (ks)
//   77824  : bias tables f32x4[(l*8+nt)*4+q], l=0(b1),1(b2),2(b3); entry r = b[16nt+4q+r]
//   79360  : b4 f32x4[q] (q==0 -> b4[0..3], else 0)            total 79424 B

typedef __attribute__((ext_vector_type(8))) short short8;
typedef __attribute__((ext_vector_type(4))) float f32x4;
typedef __attribute__((ext_vector_type(2))) float f32x2;
typedef __attribute__((ext_vector_type(4))) unsigned int u32x4;

#define MFMA(a, b, c) __builtin_amdgcn_mfma_f32_16x16x32_bf16((a), (b), (c), 0, 0, 0)

__device__ __forceinline__ unsigned short bfr(float f) {  // fp32->bf16 RNE
  unsigned u = __builtin_bit_cast(unsigned, f);
  u += 0x7FFFu + ((u >> 16) & 1u);
  return (unsigned short)(u >> 16);
}

__device__ __forceinline__ unsigned pkrelu(float a, float b) {
  a = a > 0.f ? a : 0.f;
  b = b > 0.f ? b : 0.f;
  return (unsigned)bfr(a) | ((unsigned)bfr(b) << 16);  // (lo, hi) = (a, b)
}

// B k-slot kp carries producer neuron slot p (sigma^-1):
// p = 32*(kp>>5) + 16*((kp>>2)&1) + 4*((kp>>3)&3) + (kp&3)
__device__ __forceinline__ int sig_inv(int kp) {
  return ((kp >> 5) << 5) + (((kp >> 2) & 1) << 4) + (((kp >> 3) & 3) << 2) + (kp & 3);
}

__global__ void nerf_stage(const float* __restrict__ W1, const float* __restrict__ b1,
                           const float* __restrict__ W2, const float* __restrict__ b2,
                           const float* __restrict__ W3, const float* __restrict__ b3,
                           const float* __restrict__ W4, const float* __restrict__ b4,
                           void* __restrict__ ws) {
  unsigned short* wf = (unsigned short*)ws;
  float* wb = (float*)((char*)ws + 77824);
  const int idx = blockIdx.x * 256 + threadIdx.x;
  const int stride = gridDim.x * 256;

  // A-fragments: (frag, lane) pairs
  for (int p = idx; p < 76 * 64; p += stride) {
    const int f = p >> 6, l = p & 63, m = l & 15, q = l >> 4;
    unsigned short v[8];
#pragma unroll
    for (int j = 0; j < 8; ++j) {
      float val = 0.f;
      if (f < 8) {  // L1: rows natural, K natural (only k<6, held by q==0)
        const int k = q * 8 + j;
        if (k < 6) val = W1[(f * 16 + m) * 6 + k];
      } else if (f < 72) {  // L2/L3: rows natural, cols sigma^-1-gathered
        int g = f - 8;
        const float* W = W2;
        if (g >= 32) { g -= 32; W = W3; }
        const int ks = g >> 3, nt = g & 7;
        const int c = sig_inv(ks * 32 + q * 8 + j);
        val = W[(nt * 16 + m) * 128 + c];
      } else {  // L4: only out rows m<4 exist; cols sigma^-1-gathered
        const int ks = f - 72;
        if (m < 4) val = W4[m * 128 + sig_inv(ks * 32 + q * 8 + j)];
      }
      v[j] = bfr(val);
    }
#pragma unroll
    for (int j = 0; j < 8; ++j) wf[f * 512 + l * 8 + j] = v[j];
  }

  // bias tables: 384 floats (b1..b3) + 16 floats (b4 padded)
  for (int e = idx; e < 400; e += stride) {
    float val;
    if (e < 384) {
      const int l = e >> 7, nt = (e >> 4) & 7, q = (e >> 2) & 3, r = e & 3;
      const float* b = (l == 0) ? b1 : (l == 1) ? b2 : b3;
      val = b[nt * 16 + q * 4 + r];
    } else {
      const int q = (e >> 2) & 3, r = e & 3;
      val = (q == 0) ? b4[r] : 0.f;
    }
    wb[e] = val;
  }
}

__launch_bounds__(256, 2)
__global__ void nerf_main(const float* __restrict__ x, float* __restrict__ out,
                          const unsigned short* __restrict__ wsfr,
                          const float* __restrict__ wsb, int nGroups) {
  __shared__ __align__(16) unsigned short lds[32768];  // 64 KB: W2 frags then W3 frags

  {  // stage W2/W3 frags (ws bytes 8192..73727) into LDS, coalesced 16B copies
    const u32x4* src = (const u32x4*)((const char*)wsfr + 8192);
    u32x4* dst = (u32x4*)lds;
    for (int i = threadIdx.x; i < 4096; i += 256) dst[i] = src[i];
  }
  __syncthreads();

  const int lane = threadIdx.x & 63;
  const int wid = threadIdx.x >> 6;
  const int q = lane >> 4;
  const int n = lane & 15;

  const int waveId = blockIdx.x * 4 + wid;
  const int totalWaves = gridDim.x * 4;

  // per-lane fragment pointers (short8 stride 64 == 1024 B == one frag)
  const unsigned short* lw = lds + lane * 8;
  const short8* l1f = (const short8*)(wsfr + lane * 8);              // + nt*64
  const short8* l4f = (const short8*)(wsfr + 72 * 512 + lane * 8);   // + ks*64
  const f32x4* bias = (const f32x4*)wsb + q;                         // + (l*8+nt)*4
  const f32x4* b4v = (const f32x4*)(wsb + 384) + q;

  float px[4][6] = {};
  int g = waveId;
  if (g < nGroups && q == 0) {
#pragma unroll
    for (int t = 0; t < 4; ++t) {
      const float* p = x + (g * 64 + t * 16 + n) * 6;
      f32x2 a = *(const f32x2*)p, b = *(const f32x2*)(p + 2), c = *(const f32x2*)(p + 4);
      px[t][0] = a.x; px[t][1] = a.y; px[t][2] = b.x;
      px[t][3] = b.y; px[t][4] = c.x; px[t][5] = c.y;
    }
  }

  for (; g < nGroups; g += totalWaves) {
    // ---- pack current x into layer-1 B-frags (q==0 lanes, k<6; rest zero) ----
    short8 xb[4];
#pragma unroll
    for (int t = 0; t < 4; ++t) {
      short8 v = {0, 0, 0, 0, 0, 0, 0, 0};
      if (q == 0) {
        v[0] = (short)bfr(px[t][0]); v[1] = (short)bfr(px[t][1]);
        v[2] = (short)bfr(px[t][2]); v[3] = (short)bfr(px[t][3]);
        v[4] = (short)bfr(px[t][4]); v[5] = (short)bfr(px[t][5]);
      }
      xb[t] = v;
    }
    // ---- prefetch next group's x ----
    const int gn = g + totalWaves;
    if (gn < nGroups && q == 0) {
#pragma unroll
      for (int t = 0; t < 4; ++t) {
        const float* p = x + (gn * 64 + t * 16 + n) * 6;
        f32x2 a = *(const f32x2*)p, b = *(const f32x2*)(p + 2), c = *(const f32x2*)(p + 4);
        px[t][0] = a.x; px[t][1] = a.y; px[t][2] = b.x;
        px[t][3] = b.y; px[t][4] = c.x; px[t][5] = c.y;
      }
    }

    f32x4 acc[4][8];
    short8 Bin[4][4];

    // ---- layer 1: K=32 (padded), bias as C operand ----
#pragma unroll
    for (int nt = 0; nt < 8; ++nt) {
      const short8 w = l1f[nt * 64];
      const f32x4 bv = bias[nt * 4];
#pragma unroll
      for (int t = 0; t < 4; ++t) acc[t][nt] = MFMA(w, xb[t], bv);
    }
#pragma unroll
    for (int t = 0; t < 4; ++t)
#pragma unroll
      for (int ks = 0; ks < 4; ++ks) {
        u32x4 u;
        u.x = pkrelu(acc[t][2 * ks].x, acc[t][2 * ks].y);
        u.y = pkrelu(acc[t][2 * ks].z, acc[t][2 * ks].w);
        u.z = pkrelu(acc[t][2 * ks + 1].x, acc[t][2 * ks + 1].y);
        u.w = pkrelu(acc[t][2 * ks + 1].z, acc[t][2 * ks + 1].w);
        Bin[t][ks] = __builtin_bit_cast(short8, u);
      }

    // ---- layer 2: W2 frags from LDS ----
#pragma unroll
    for (int ks = 0; ks < 4; ++ks) {
#pragma unroll
      for (int nt = 0; nt < 8; ++nt) {
        const short8 w = *(const short8*)(lw + (ks * 8 + nt) * 512);
        if (ks == 0) {
          const f32x4 bv = bias[(8 + nt) * 4];
#pragma unroll
          for (int t = 0; t < 4; ++t) acc[t][nt] = MFMA(w, Bin[t][0], bv);
        } else {
#pragma unroll
          for (int t = 0; t < 4; ++t) acc[t][nt] = MFMA(w, Bin[t][ks], acc[t][nt]);
        }
      }
    }
#pragma unroll
    for (int t = 0; t < 4; ++t)
#pragma unroll
      for (int ks = 0; ks < 4; ++ks) {
        u32x4 u;
        u.x = pkrelu(acc[t][2 * ks].x, acc[t][2 * ks].y);
        u.y = pkrelu(acc[t][2 * ks].z, acc[t][2 * ks].w);
        u.z = pkrelu(acc[t][2 * ks + 1].x, acc[t][2 * ks + 1].y);
        u.w = pkrelu(acc[t][2 * ks + 1].z, acc[t][2 * ks + 1].w);
        Bin[t][ks] = __builtin_bit_cast(short8, u);
      }

    // ---- layer 3: W3 frags from LDS ----
#pragma unroll
    for (int ks = 0; ks < 4; ++ks) {
#pragma unroll
      for (int nt = 0; nt < 8; ++nt) {
        const short8 w = *(const short8*)(lw + (32 + ks * 8 + nt) * 512);
        if (ks == 0) {
          const f32x4 bv = bias[(16 + nt) * 4];
#pragma unroll
          for (int t = 0; t < 4; ++t) acc[t][nt] = MFMA(w, Bin[t][0], bv);
        } else {
#pragma unroll
          for (int t = 0; t < 4; ++t) acc[t][nt] = MFMA(w, Bin[t][ks], acc[t][nt]);
        }
      }
    }
#pragma unroll
    for (int t = 0; t < 4; ++t)
#pragma unroll
      for (int ks = 0; ks < 4; ++ks) {
        u32x4 u;
        u.x = pkrelu(acc[t][2 * ks].x, acc[t][2 * ks].y);
        u.y = pkrelu(acc[t][2 * ks].z, acc[t][2 * ks].w);
        u.z = pkrelu(acc[t][2 * ks + 1].x, acc[t][2 * ks + 1].y);
        u.w = pkrelu(acc[t][2 * ks + 1].z, acc[t][2 * ks + 1].w);
        Bin[t][ks] = __builtin_bit_cast(short8, u);
      }

    // ---- layer 4: 1 m-tile (out neurons 0..3 at q==0) ----
    f32x4 o[4];
    {
      const f32x4 bv = b4v[0];
#pragma unroll
      for (int ks = 0; ks < 4; ++ks) {
        const short8 w = l4f[ks * 64];
        if (ks == 0) {
#pragma unroll
          for (int t = 0; t < 4; ++t) o[t] = MFMA(w, Bin[t][0], bv);
        } else {
#pragma unroll
          for (int t = 0; t < 4; ++t) o[t] = MFMA(w, Bin[t][ks], o[t]);
        }
      }
    }
    if (q == 0) {  // lane n holds out row (g*64+t*16+n), cols 0..3 in o[t]
#pragma unroll
      for (int t = 0; t < 4; ++t)
        *(f32x4*)(out + (g * 64 + t * 16 + n) * 4) = o[t];
    }
  }
}

extern "C" void kernel_launch(void* const* d_in, const int* in_sizes, int n_in,
                              void* d_out, int out_size, void* d_ws, size_t ws_size,
                              hipStream_t stream) {
  const float* x  = (const float*)d_in[0];
  const float* W1 = (const float*)d_in[1];
  const float* b1 = (const float*)d_in[2];
  const float* W2 = (const float*)d_in[3];
  const float* b2 = (const float*)d_in[4];
  const float* W3 = (const float*)d_in[5];
  const float* b3 = (const float*)d_in[6];
  const float* W4 = (const float*)d_in[7];
  const float* b4 = (const float*)d_in[8];
  float* out = (float*)d_out;

  const int N = in_sizes[0] / 6;
  const int nGroups = N / 64;  // 4 tiles of 16 rows per wave-iteration

  nerf_stage<<<dim3(4), dim3(256), 0, stream>>>(W1, b1, W2, b2, W3, b3, W4, b4, d_ws);

  const unsigned short* wsfr = (const unsigned short*)d_ws;
  const float* wsb = (const float*)((const char*)d_ws + 77824);
  // 512 blocks = 2/CU (8 waves/CU at launch_bounds(256,2)); 2048 waves x 8 iters
  nerf_main<<<dim3(512), dim3(256), 0, stream>>>(x, out, wsfr, wsb, nGroups);
}

// Round 5
// 361.248 us; speedup vs baseline: 1.1508x; 1.1508x over previous
//
#include <hip/hip_runtime.h>

// R5 = R4 with the macro/braced-init compile fix (named zero f32x4).
// Transposed fused MLP, spill-proofed:
//  - Paired-nt accumulation: 8 live acc regs per tile instead of 32.
//  - T=2 row-tiles per wave-iter: peak live ~230 regs < 256 cap (no scratch).
//  - Steady state touches global ONLY for x (prefetched) and out:
//    W2/W3 frags in 64 KB static LDS; L1/L4 frags + b2/b3/b4 in persistent
//    registers; b1 folded into L1 fragment k-slot 6 (B-side k6 = 1.0).
//  - pkrelu via v_cvt_pk_bf16_f32 when available.
//
// ws layout (bytes), written by nerf_stage:
//   0      : 76 A-frags, 1024 B each (frag f: lane l holds short8 at f*1024+l*16)
//            f 0..7 = L1 (nt; k=0..5 W1, k=6 b1) | 8..39 = L2 (ks*8+nt)
//            | 40..71 = L3 | 72..75 = L4 (ks)
//   77824  : bias tables f32x4[(l*8+nt)*4+q], l=0(b1,unused),1(b2),2(b3)
//   79360  : b4 f32x4[q] (q==0 -> b4[0..3], else 0)

typedef __attribute__((ext_vector_type(8))) short short8;
typedef __attribute__((ext_vector_type(4))) float f32x4;
typedef __attribute__((ext_vector_type(2))) float f32x2;
typedef __attribute__((ext_vector_type(4))) unsigned int u32x4;

#define MFMA(a, b, c) __builtin_amdgcn_mfma_f32_16x16x32_bf16((a), (b), (c), 0, 0, 0)

__device__ __forceinline__ unsigned short bfr(float f) {  // fp32->bf16 RNE
  unsigned u = __builtin_bit_cast(unsigned, f);
  u += 0x7FFFu + ((u >> 16) & 1u);
  return (unsigned short)(u >> 16);
}

__device__ __forceinline__ unsigned pkrelu(float a, float b) {
  a = __builtin_fmaxf(a, 0.f);
  b = __builtin_fmaxf(b, 0.f);
#if __has_builtin(__builtin_amdgcn_cvt_pk_bf16_f32)
  auto h = __builtin_amdgcn_cvt_pk_bf16_f32(a, b);
  return __builtin_bit_cast(unsigned, h);
#else
  return (unsigned)bfr(a) | ((unsigned)bfr(b) << 16);
#endif
}

__device__ __forceinline__ short8 pack4(const f32x4& a0, const f32x4& a1) {
  u32x4 u;
  u.x = pkrelu(a0.x, a0.y);
  u.y = pkrelu(a0.z, a0.w);
  u.z = pkrelu(a1.x, a1.y);
  u.w = pkrelu(a1.z, a1.w);
  return __builtin_bit_cast(short8, u);
}

// B k-slot kp carries producer neuron slot p (sigma^-1):
// p = 32*(kp>>5) + 16*((kp>>2)&1) + 4*((kp>>3)&3) + (kp&3)
__device__ __forceinline__ int sig_inv(int kp) {
  return ((kp >> 5) << 5) + (((kp >> 2) & 1) << 4) + (((kp >> 3) & 3) << 2) + (kp & 3);
}

__global__ void nerf_stage(const float* __restrict__ W1, const float* __restrict__ b1,
                           const float* __restrict__ W2, const float* __restrict__ b2,
                           const float* __restrict__ W3, const float* __restrict__ b3,
                           const float* __restrict__ W4, const float* __restrict__ b4,
                           void* __restrict__ ws) {
  unsigned short* wf = (unsigned short*)ws;
  float* wb = (float*)((char*)ws + 77824);
  const int idx = blockIdx.x * 256 + threadIdx.x;
  const int stride = gridDim.x * 256;

  for (int p = idx; p < 76 * 64; p += stride) {
    const int f = p >> 6, l = p & 63, m = l & 15, q = l >> 4;
    unsigned short v[8];
#pragma unroll
    for (int j = 0; j < 8; ++j) {
      float val = 0.f;
      if (f < 8) {  // L1: k<6 = W1 row, k==6 = b1 (bias slot; B provides 1.0)
        const int k = q * 8 + j;
        if (k < 6) val = W1[(f * 16 + m) * 6 + k];
        else if (k == 6) val = b1[f * 16 + m];
      } else if (f < 72) {  // L2/L3: cols sigma^-1-gathered
        int g = f - 8;
        const float* W = W2;
        if (g >= 32) { g -= 32; W = W3; }
        const int ks = g >> 3, nt = g & 7;
        val = W[(nt * 16 + m) * 128 + sig_inv(ks * 32 + q * 8 + j)];
      } else {  // L4: out rows m<4 only
        const int ks = f - 72;
        if (m < 4) val = W4[m * 128 + sig_inv(ks * 32 + q * 8 + j)];
      }
      v[j] = bfr(val);
    }
#pragma unroll
    for (int j = 0; j < 8; ++j) wf[f * 512 + l * 8 + j] = v[j];
  }

  for (int e = idx; e < 400; e += stride) {
    float val;
    if (e < 384) {
      const int l = e >> 7, nt = (e >> 4) & 7, q = (e >> 2) & 3, r = e & 3;
      const float* b = (l == 0) ? b1 : (l == 1) ? b2 : b3;
      val = b[nt * 16 + q * 4 + r];
    } else {
      const int q = (e >> 2) & 3, r = e & 3;
      val = (q == 0) ? b4[r] : 0.f;
    }
    wb[e] = val;
  }
}

__launch_bounds__(256, 2)
__global__ void nerf_main(const float* __restrict__ x, float* __restrict__ out,
                          const unsigned short* __restrict__ wsfr,
                          const float* __restrict__ wsb, int nGroups) {
  __shared__ __align__(16) unsigned short lds[32768];  // exactly 64 KB: W2 | W3 frags

  {  // stage W2/W3 frags (ws bytes 8192..73727) into LDS
    const u32x4* src = (const u32x4*)((const char*)wsfr + 8192);
    u32x4* dst = (u32x4*)lds;
    for (int i = threadIdx.x; i < 4096; i += 256) dst[i] = src[i];
  }
  __syncthreads();

  const int lane = threadIdx.x & 63;
  const int wid = threadIdx.x >> 6;
  const int q = lane >> 4;
  const int n = lane & 15;

  const int waveId = blockIdx.x * 4 + wid;
  const int totalWaves = gridDim.x * 4;

  const unsigned short* lw = lds + lane * 8;  // + (frag)*512

  // ---- persistent register state: L1/L4 frags, b2/b3/b4 ----
  short8 l1f[8], l4f[4];
  {
    const short8* p1 = (const short8*)(wsfr + lane * 8);
    const short8* p4 = (const short8*)(wsfr + 72 * 512 + lane * 8);
#pragma unroll
    for (int nt = 0; nt < 8; ++nt) l1f[nt] = p1[nt * 64];
#pragma unroll
    for (int ks = 0; ks < 4; ++ks) l4f[ks] = p4[ks * 64];
  }
  f32x4 bias2[8], bias3[8], b4v;
  {
    const f32x4* bp = (const f32x4*)wsb;
#pragma unroll
    for (int nt = 0; nt < 8; ++nt) {
      bias2[nt] = bp[(8 + nt) * 4 + q];
      bias3[nt] = bp[(16 + nt) * 4 + q];
    }
    b4v = ((const f32x4*)(wsb + 384))[q];
  }

  const f32x4 zf = {0.f, 0.f, 0.f, 0.f};

  float px[2][6] = {};
  int g = waveId;
  if (g < nGroups && q == 0) {
#pragma unroll
    for (int t = 0; t < 2; ++t) {
      const float* p = x + (g * 32 + t * 16 + n) * 6;
      f32x2 a = *(const f32x2*)p, b = *(const f32x2*)(p + 2), c = *(const f32x2*)(p + 4);
      px[t][0] = a.x; px[t][1] = a.y; px[t][2] = b.x;
      px[t][3] = b.y; px[t][4] = c.x; px[t][5] = c.y;
    }
  }

  for (; g < nGroups; g += totalWaves) {
    // ---- x -> layer-1 B frags (q==0: k0..5 = x, k6 = 1.0 for the bias slot) ----
    short8 xb[2];
#pragma unroll
    for (int t = 0; t < 2; ++t) {
      short8 v = {0, 0, 0, 0, 0, 0, 0, 0};
      if (q == 0) {
        v[0] = (short)bfr(px[t][0]); v[1] = (short)bfr(px[t][1]);
        v[2] = (short)bfr(px[t][2]); v[3] = (short)bfr(px[t][3]);
        v[4] = (short)bfr(px[t][4]); v[5] = (short)bfr(px[t][5]);
        v[6] = (short)0x3F80;  // bf16 1.0
      }
      xb[t] = v;
    }
    const int gn = g + totalWaves;
    if (gn < nGroups && q == 0) {
#pragma unroll
      for (int t = 0; t < 2; ++t) {
        const float* p = x + (gn * 32 + t * 16 + n) * 6;
        f32x2 a = *(const f32x2*)p, b = *(const f32x2*)(p + 2), c = *(const f32x2*)(p + 4);
        px[t][0] = a.x; px[t][1] = a.y; px[t][2] = b.x;
        px[t][3] = b.y; px[t][4] = c.x; px[t][5] = c.y;
      }
    }

    short8 B1[2][4], B2[2][4];

    // ---- layer 1 (bias in k-slot 6, C=0) ----
#pragma unroll
    for (int ntp = 0; ntp < 4; ++ntp) {
      f32x4 a0[2], a1[2];
#pragma unroll
      for (int t = 0; t < 2; ++t) {
        a0[t] = MFMA(l1f[2 * ntp], xb[t], zf);
        a1[t] = MFMA(l1f[2 * ntp + 1], xb[t], zf);
      }
#pragma unroll
      for (int t = 0; t < 2; ++t) B1[t][ntp] = pack4(a0[t], a1[t]);
    }

    // ---- layer 2 (W2 frags from LDS, bias as C at ks==0) ----
#pragma unroll
    for (int ntp = 0; ntp < 4; ++ntp) {
      f32x4 a0[2], a1[2];
#pragma unroll
      for (int ks = 0; ks < 4; ++ks) {
        const short8 w0 = *(const short8*)(lw + (ks * 8 + 2 * ntp) * 512);
        const short8 w1 = *(const short8*)(lw + (ks * 8 + 2 * ntp + 1) * 512);
        if (ks == 0) {
#pragma unroll
          for (int t = 0; t < 2; ++t) {
            a0[t] = MFMA(w0, B1[t][0], bias2[2 * ntp]);
            a1[t] = MFMA(w1, B1[t][0], bias2[2 * ntp + 1]);
          }
        } else {
#pragma unroll
          for (int t = 0; t < 2; ++t) {
            a0[t] = MFMA(w0, B1[t][ks], a0[t]);
            a1[t] = MFMA(w1, B1[t][ks], a1[t]);
          }
        }
      }
#pragma unroll
      for (int t = 0; t < 2; ++t) B2[t][ntp] = pack4(a0[t], a1[t]);
    }

    // ---- layer 3 (W3 frags from LDS) ----
#pragma unroll
    for (int ntp = 0; ntp < 4; ++ntp) {
      f32x4 a0[2], a1[2];
#pragma unroll
      for (int ks = 0; ks < 4; ++ks) {
        const short8 w0 = *(const short8*)(lw + (32 + ks * 8 + 2 * ntp) * 512);
        const short8 w1 = *(const short8*)(lw + (32 + ks * 8 + 2 * ntp + 1) * 512);
        if (ks == 0) {
#pragma unroll
          for (int t = 0; t < 2; ++t) {
            a0[t] = MFMA(w0, B2[t][0], bias3[2 * ntp]);
            a1[t] = MFMA(w1, B2[t][0], bias3[2 * ntp + 1]);
          }
        } else {
#pragma unroll
          for (int t = 0; t < 2; ++t) {
            a0[t] = MFMA(w0, B2[t][ks], a0[t]);
            a1[t] = MFMA(w1, B2[t][ks], a1[t]);
          }
        }
      }
#pragma unroll
      for (int t = 0; t < 2; ++t) B1[t][ntp] = pack4(a0[t], a1[t]);  // reuse B1
    }

    // ---- layer 4 (frags in regs; out rows at q==0) ----
    f32x4 o[2];
#pragma unroll
    for (int ks = 0; ks < 4; ++ks) {
      if (ks == 0) {
#pragma unroll
        for (int t = 0; t < 2; ++t) o[t] = MFMA(l4f[0], B1[t][0], b4v);
      } else {
#pragma unroll
        for (int t = 0; t < 2; ++t) o[t] = MFMA(l4f[ks], B1[t][ks], o[t]);
      }
    }
    if (q == 0) {
#pragma unroll
      for (int t = 0; t < 2; ++t)
        *(f32x4*)(out + (g * 32 + t * 16 + n) * 4) = o[t];
    }
  }
}

extern "C" void kernel_launch(void* const* d_in, const int* in_sizes, int n_in,
                              void* d_out, int out_size, void* d_ws, size_t ws_size,
                              hipStream_t stream) {
  const float* x  = (const float*)d_in[0];
  const float* W1 = (const float*)d_in[1];
  const float* b1 = (const float*)d_in[2];
  const float* W2 = (const float*)d_in[3];
  const float* b2 = (const float*)d_in[4];
  const float* W3 = (const float*)d_in[5];
  const float* b3 = (const float*)d_in[6];
  const float* W4 = (const float*)d_in[7];
  const float* b4 = (const float*)d_in[8];
  float* out = (float*)d_out;

  const int N = in_sizes[0] / 6;
  const int nGroups = N / 32;  // 2 tiles of 16 rows per wave-iteration -> 32768

  nerf_stage<<<dim3(4), dim3(256), 0, stream>>>(W1, b1, W2, b2, W3, b3, W4, b4, d_ws);

  const unsigned short* wsfr = (const unsigned short*)d_ws;
  const float* wsb = (const float*)((const char*)d_ws + 77824);
  // 512 blocks = 2/CU (8 waves/CU); 2048 waves x exactly 16 iterations
  nerf_main<<<dim3(512), dim3(256), 0, stream>>>(x, out, wsfr, wsb, nGroups);
}

// Round 6
// 361.121 us; speedup vs baseline: 1.1512x; 1.0004x over previous
//
#include <hip/hip_runtime.h>

// R6 = R5 + amdgpu_waves_per_eu(2,2) pin.
// R5's counters showed the allocator chose 4 waves/EU (VGPR_Count=128) for a
// ~236-reg design -> remat of "persistent" weight/bias loads inside the loop
// (881 MB FETCH) + scratch spill (125 MB WRITE). Pinning 2 waves/EU gives the
// 256-reg budget the design was built for; body unchanged.
//
// ws layout (bytes), written by nerf_stage:
//   0      : 76 A-frags, 1024 B each (frag f: lane l holds short8 at f*1024+l*16)
//            f 0..7 = L1 (nt; k=0..5 W1, k=6 b1) | 8..39 = L2 (ks*8+nt)
//            | 40..71 = L3 | 72..75 = L4 (ks)
//   77824  : bias tables f32x4[(l*8+nt)*4+q], l=0(b1,unused),1(b2),2(b3)
//   79360  : b4 f32x4[q] (q==0 -> b4[0..3], else 0)

typedef __attribute__((ext_vector_type(8))) short short8;
typedef __attribute__((ext_vector_type(4))) float f32x4;
typedef __attribute__((ext_vector_type(2))) float f32x2;
typedef __attribute__((ext_vector_type(4))) unsigned int u32x4;

#define MFMA(a, b, c) __builtin_amdgcn_mfma_f32_16x16x32_bf16((a), (b), (c), 0, 0, 0)

__device__ __forceinline__ unsigned short bfr(float f) {  // fp32->bf16 RNE
  unsigned u = __builtin_bit_cast(unsigned, f);
  u += 0x7FFFu + ((u >> 16) & 1u);
  return (unsigned short)(u >> 16);
}

__device__ __forceinline__ unsigned pkrelu(float a, float b) {
  a = __builtin_fmaxf(a, 0.f);
  b = __builtin_fmaxf(b, 0.f);
#if __has_builtin(__builtin_amdgcn_cvt_pk_bf16_f32)
  auto h = __builtin_amdgcn_cvt_pk_bf16_f32(a, b);
  return __builtin_bit_cast(unsigned, h);
#else
  return (unsigned)bfr(a) | ((unsigned)bfr(b) << 16);
#endif
}

__device__ __forceinline__ short8 pack4(const f32x4& a0, const f32x4& a1) {
  u32x4 u;
  u.x = pkrelu(a0.x, a0.y);
  u.y = pkrelu(a0.z, a0.w);
  u.z = pkrelu(a1.x, a1.y);
  u.w = pkrelu(a1.z, a1.w);
  return __builtin_bit_cast(short8, u);
}

// B k-slot kp carries producer neuron slot p (sigma^-1):
// p = 32*(kp>>5) + 16*((kp>>2)&1) + 4*((kp>>3)&3) + (kp&3)
__device__ __forceinline__ int sig_inv(int kp) {
  return ((kp >> 5) << 5) + (((kp >> 2) & 1) << 4) + (((kp >> 3) & 3) << 2) + (kp & 3);
}

__global__ void nerf_stage(const float* __restrict__ W1, const float* __restrict__ b1,
                           const float* __restrict__ W2, const float* __restrict__ b2,
                           const float* __restrict__ W3, const float* __restrict__ b3,
                           const float* __restrict__ W4, const float* __restrict__ b4,
                           void* __restrict__ ws) {
  unsigned short* wf = (unsigned short*)ws;
  float* wb = (float*)((char*)ws + 77824);
  const int idx = blockIdx.x * 256 + threadIdx.x;
  const int stride = gridDim.x * 256;

  for (int p = idx; p < 76 * 64; p += stride) {
    const int f = p >> 6, l = p & 63, m = l & 15, q = l >> 4;
    unsigned short v[8];
#pragma unroll
    for (int j = 0; j < 8; ++j) {
      float val = 0.f;
      if (f < 8) {  // L1: k<6 = W1 row, k==6 = b1 (bias slot; B provides 1.0)
        const int k = q * 8 + j;
        if (k < 6) val = W1[(f * 16 + m) * 6 + k];
        else if (k == 6) val = b1[f * 16 + m];
      } else if (f < 72) {  // L2/L3: cols sigma^-1-gathered
        int g = f - 8;
        const float* W = W2;
        if (g >= 32) { g -= 32; W = W3; }
        const int ks = g >> 3, nt = g & 7;
        val = W[(nt * 16 + m) * 128 + sig_inv(ks * 32 + q * 8 + j)];
      } else {  // L4: out rows m<4 only
        const int ks = f - 72;
        if (m < 4) val = W4[m * 128 + sig_inv(ks * 32 + q * 8 + j)];
      }
      v[j] = bfr(val);
    }
#pragma unroll
    for (int j = 0; j < 8; ++j) wf[f * 512 + l * 8 + j] = v[j];
  }

  for (int e = idx; e < 400; e += stride) {
    float val;
    if (e < 384) {
      const int l = e >> 7, nt = (e >> 4) & 7, q = (e >> 2) & 3, r = e & 3;
      const float* b = (l == 0) ? b1 : (l == 1) ? b2 : b3;
      val = b[nt * 16 + q * 4 + r];
    } else {
      const int q = (e >> 2) & 3, r = e & 3;
      val = (q == 0) ? b4[r] : 0.f;
    }
    wb[e] = val;
  }
}

__attribute__((amdgpu_waves_per_eu(2, 2)))
__launch_bounds__(256)
__global__ void nerf_main(const float* __restrict__ x, float* __restrict__ out,
                          const unsigned short* __restrict__ wsfr,
                          const float* __restrict__ wsb, int nGroups) {
  __shared__ __align__(16) unsigned short lds[32768];  // exactly 64 KB: W2 | W3 frags

  {  // stage W2/W3 frags (ws bytes 8192..73727) into LDS
    const u32x4* src = (const u32x4*)((const char*)wsfr + 8192);
    u32x4* dst = (u32x4*)lds;
    for (int i = threadIdx.x; i < 4096; i += 256) dst[i] = src[i];
  }
  __syncthreads();

  const int lane = threadIdx.x & 63;
  const int wid = threadIdx.x >> 6;
  const int q = lane >> 4;
  const int n = lane & 15;

  const int waveId = blockIdx.x * 4 + wid;
  const int totalWaves = gridDim.x * 4;

  const unsigned short* lw = lds + lane * 8;  // + (frag)*512

  // ---- persistent register state: L1/L4 frags, b2/b3/b4 ----
  short8 l1f[8], l4f[4];
  {
    const short8* p1 = (const short8*)(wsfr + lane * 8);
    const short8* p4 = (const short8*)(wsfr + 72 * 512 + lane * 8);
#pragma unroll
    for (int nt = 0; nt < 8; ++nt) l1f[nt] = p1[nt * 64];
#pragma unroll
    for (int ks = 0; ks < 4; ++ks) l4f[ks] = p4[ks * 64];
  }
  f32x4 bias2[8], bias3[8], b4v;
  {
    const f32x4* bp = (const f32x4*)wsb;
#pragma unroll
    for (int nt = 0; nt < 8; ++nt) {
      bias2[nt] = bp[(8 + nt) * 4 + q];
      bias3[nt] = bp[(16 + nt) * 4 + q];
    }
    b4v = ((const f32x4*)(wsb + 384))[q];
  }

  const f32x4 zf = {0.f, 0.f, 0.f, 0.f};

  float px[2][6] = {};
  int g = waveId;
  if (g < nGroups && q == 0) {
#pragma unroll
    for (int t = 0; t < 2; ++t) {
      const float* p = x + (g * 32 + t * 16 + n) * 6;
      f32x2 a = *(const f32x2*)p, b = *(const f32x2*)(p + 2), c = *(const f32x2*)(p + 4);
      px[t][0] = a.x; px[t][1] = a.y; px[t][2] = b.x;
      px[t][3] = b.y; px[t][4] = c.x; px[t][5] = c.y;
    }
  }

  for (; g < nGroups; g += totalWaves) {
    // ---- x -> layer-1 B frags (q==0: k0..5 = x, k6 = 1.0 for the bias slot) ----
    short8 xb[2];
#pragma unroll
    for (int t = 0; t < 2; ++t) {
      short8 v = {0, 0, 0, 0, 0, 0, 0, 0};
      if (q == 0) {
        v[0] = (short)bfr(px[t][0]); v[1] = (short)bfr(px[t][1]);
        v[2] = (short)bfr(px[t][2]); v[3] = (short)bfr(px[t][3]);
        v[4] = (short)bfr(px[t][4]); v[5] = (short)bfr(px[t][5]);
        v[6] = (short)0x3F80;  // bf16 1.0
      }
      xb[t] = v;
    }
    const int gn = g + totalWaves;
    if (gn < nGroups && q == 0) {
#pragma unroll
      for (int t = 0; t < 2; ++t) {
        const float* p = x + (gn * 32 + t * 16 + n) * 6;
        f32x2 a = *(const f32x2*)p, b = *(const f32x2*)(p + 2), c = *(const f32x2*)(p + 4);
        px[t][0] = a.x; px[t][1] = a.y; px[t][2] = b.x;
        px[t][3] = b.y; px[t][4] = c.x; px[t][5] = c.y;
      }
    }

    short8 B1[2][4], B2[2][4];

    // ---- layer 1 (bias in k-slot 6, C=0) ----
#pragma unroll
    for (int ntp = 0; ntp < 4; ++ntp) {
      f32x4 a0[2], a1[2];
#pragma unroll
      for (int t = 0; t < 2; ++t) {
        a0[t] = MFMA(l1f[2 * ntp], xb[t], zf);
        a1[t] = MFMA(l1f[2 * ntp + 1], xb[t], zf);
      }
#pragma unroll
      for (int t = 0; t < 2; ++t) B1[t][ntp] = pack4(a0[t], a1[t]);
    }

    // ---- layer 2 (W2 frags from LDS, bias as C at ks==0) ----
#pragma unroll
    for (int ntp = 0; ntp < 4; ++ntp) {
      f32x4 a0[2], a1[2];
#pragma unroll
      for (int ks = 0; ks < 4; ++ks) {
        const short8 w0 = *(const short8*)(lw + (ks * 8 + 2 * ntp) * 512);
        const short8 w1 = *(const short8*)(lw + (ks * 8 + 2 * ntp + 1) * 512);
        if (ks == 0) {
#pragma unroll
          for (int t = 0; t < 2; ++t) {
            a0[t] = MFMA(w0, B1[t][0], bias2[2 * ntp]);
            a1[t] = MFMA(w1, B1[t][0], bias2[2 * ntp + 1]);
          }
        } else {
#pragma unroll
          for (int t = 0; t < 2; ++t) {
            a0[t] = MFMA(w0, B1[t][ks], a0[t]);
            a1[t] = MFMA(w1, B1[t][ks], a1[t]);
          }
        }
      }
#pragma unroll
      for (int t = 0; t < 2; ++t) B2[t][ntp] = pack4(a0[t], a1[t]);
    }

    // ---- layer 3 (W3 frags from LDS) ----
#pragma unroll
    for (int ntp = 0; ntp < 4; ++ntp) {
      f32x4 a0[2], a1[2];
#pragma unroll
      for (int ks = 0; ks < 4; ++ks) {
        const short8 w0 = *(const short8*)(lw + (32 + ks * 8 + 2 * ntp) * 512);
        const short8 w1 = *(const short8*)(lw + (32 + ks * 8 + 2 * ntp + 1) * 512);
        if (ks == 0) {
#pragma unroll
          for (int t = 0; t < 2; ++t) {
            a0[t] = MFMA(w0, B2[t][0], bias3[2 * ntp]);
            a1[t] = MFMA(w1, B2[t][0], bias3[2 * ntp + 1]);
          }
        } else {
#pragma unroll
          for (int t = 0; t < 2; ++t) {
            a0[t] = MFMA(w0, B2[t][ks], a0[t]);
            a1[t] = MFMA(w1, B2[t][ks], a1[t]);
          }
        }
      }
#pragma unroll
      for (int t = 0; t < 2; ++t) B1[t][ntp] = pack4(a0[t], a1[t]);  // reuse B1
    }

    // ---- layer 4 (frags in regs; out rows at q==0) ----
    f32x4 o[2];
#pragma unroll
    for (int ks = 0; ks < 4; ++ks) {
      if (ks == 0) {
#pragma unroll
        for (int t = 0; t < 2; ++t) o[t] = MFMA(l4f[0], B1[t][0], b4v);
      } else {
#pragma unroll
        for (int t = 0; t < 2; ++t) o[t] = MFMA(l4f[ks], B1[t][ks], o[t]);
      }
    }
    if (q == 0) {
#pragma unroll
      for (int t = 0; t < 2; ++t)
        *(f32x4*)(out + (g * 32 + t * 16 + n) * 4) = o[t];
    }
  }
}

extern "C" void kernel_launch(void* const* d_in, const int* in_sizes, int n_in,
                              void* d_out, int out_size, void* d_ws, size_t ws_size,
                              hipStream_t stream) {
  const float* x  = (const float*)d_in[0];
  const float* W1 = (const float*)d_in[1];
  const float* b1 = (const float*)d_in[2];
  const float* W2 = (const float*)d_in[3];
  const float* b2 = (const float*)d_in[4];
  const float* W3 = (const float*)d_in[5];
  const float* b3 = (const float*)d_in[6];
  const float* W4 = (const float*)d_in[7];
  const float* b4 = (const float*)d_in[8];
  float* out = (float*)d_out;

  const int N = in_sizes[0] / 6;
  const int nGroups = N / 32;  // 2 tiles of 16 rows per wave-iteration -> 32768

  nerf_stage<<<dim3(4), dim3(256), 0, stream>>>(W1, b1, W2, b2, W3, b3, W4, b4, d_ws);

  const unsigned short* wsfr = (const unsigned short*)d_ws;
  const float* wsb = (const float*)((const char*)d_ws + 77824);
  // 512 blocks = 2/CU (8 waves/CU pinned by waves_per_eu(2,2))
  nerf_main<<<dim3(512), dim3(256), 0, stream>>>(x, out, wsfr, wsb, nGroups);
}

// Round 7
// 212.631 us; speedup vs baseline: 1.9552x; 1.6983x over previous
//
#include <hip/hip_runtime.h>

// R7: all constants in LDS — design fits the allocator's 128-VGPR budget.
// R5/R6 showed the allocator pins this kernel at 128 regs regardless of
// launch_bounds/waves_per_eu, rematerializing "persistent" weight registers
// from global every iteration (881 MB FETCH) and spilling B-frags (125 MB
// WRITE). R7 keeps ONLY loop state in registers (~118 peak) and serves all
// weights/biases from the 77 KB block LDS slab: L1 frags, W2, W3, L4 frags,
// and bias tables (read as broadcast ds_read_b128 C-operands).
//
// ws/LDS layout (bytes), written by nerf_stage, copied whole to LDS:
//   0      : 76 A-frags, 1024 B each (frag f: lane l holds short8 at f*1024+l*16)
//            f 0..7 = L1 (nt; k=0..5 W1, k=6 b1) | 8..39 = L2 (ks*8+nt)
//            | 40..71 = L3 (ks*8+nt) | 72..75 = L4 (ks)
//   77824  : bias2 = straight copy of b2[0..127]  (f32x4 entry nt*4+q)
//   78336  : bias3 = straight copy of b3[0..127]
//   78848  : b4 padded: q==0 -> b4[0..3], else 0   (f32x4 entry q)
//   total 78912 B  (77.1 KB -> 2 blocks/CU at 160 KB LDS)

typedef __attribute__((ext_vector_type(8))) short short8;
typedef __attribute__((ext_vector_type(4))) float f32x4;
typedef __attribute__((ext_vector_type(2))) float f32x2;
typedef __attribute__((ext_vector_type(4))) unsigned int u32x4;

#define MFMA(a, b, c) __builtin_amdgcn_mfma_f32_16x16x32_bf16((a), (b), (c), 0, 0, 0)

__device__ __forceinline__ unsigned short bfr(float f) {  // fp32->bf16 RNE
  unsigned u = __builtin_bit_cast(unsigned, f);
  u += 0x7FFFu + ((u >> 16) & 1u);
  return (unsigned short)(u >> 16);
}

__device__ __forceinline__ unsigned pkrelu(float a, float b) {
  a = __builtin_fmaxf(a, 0.f);
  b = __builtin_fmaxf(b, 0.f);
#if __has_builtin(__builtin_amdgcn_cvt_pk_bf16_f32)
  auto h = __builtin_amdgcn_cvt_pk_bf16_f32(a, b);
  return __builtin_bit_cast(unsigned, h);
#else
  return (unsigned)bfr(a) | ((unsigned)bfr(b) << 16);
#endif
}

__device__ __forceinline__ short8 pack4(const f32x4& a0, const f32x4& a1) {
  u32x4 u;
  u.x = pkrelu(a0.x, a0.y);
  u.y = pkrelu(a0.z, a0.w);
  u.z = pkrelu(a1.x, a1.y);
  u.w = pkrelu(a1.z, a1.w);
  return __builtin_bit_cast(short8, u);
}

// consumer B k-slot kp <- producer neuron slot sig_inv(kp)
__device__ __forceinline__ int sig_inv(int kp) {
  return ((kp >> 5) << 5) + (((kp >> 2) & 1) << 4) + (((kp >> 3) & 3) << 2) + (kp & 3);
}

__global__ void nerf_stage(const float* __restrict__ W1, const float* __restrict__ b1,
                           const float* __restrict__ W2, const float* __restrict__ b2,
                           const float* __restrict__ W3, const float* __restrict__ b3,
                           const float* __restrict__ W4, const float* __restrict__ b4,
                           void* __restrict__ ws) {
  unsigned short* wf = (unsigned short*)ws;
  float* wb = (float*)((char*)ws + 77824);
  const int idx = blockIdx.x * 256 + threadIdx.x;
  const int stride = gridDim.x * 256;

  for (int p = idx; p < 76 * 64; p += stride) {
    const int f = p >> 6, l = p & 63, m = l & 15, q = l >> 4;
    unsigned short v[8];
#pragma unroll
    for (int j = 0; j < 8; ++j) {
      float val = 0.f;
      if (f < 8) {  // L1: k<6 = W1 row, k==6 = b1 (B-side supplies 1.0)
        const int k = q * 8 + j;
        if (k < 6) val = W1[(f * 16 + m) * 6 + k];
        else if (k == 6) val = b1[f * 16 + m];
      } else if (f < 72) {  // L2/L3: cols sigma^-1-gathered
        int g = f - 8;
        const float* W = W2;
        if (g >= 32) { g -= 32; W = W3; }
        const int ks = g >> 3, nt = g & 7;
        val = W[(nt * 16 + m) * 128 + sig_inv(ks * 32 + q * 8 + j)];
      } else {  // L4: out rows m<4 only
        const int ks = f - 72;
        if (m < 4) val = W4[m * 128 + sig_inv(ks * 32 + q * 8 + j)];
      }
      v[j] = bfr(val);
    }
#pragma unroll
    for (int j = 0; j < 8; ++j) wf[f * 512 + l * 8 + j] = v[j];
  }

  // 272 floats: b2 copy | b3 copy | b4 padded to 4 quads
  for (int e = idx; e < 272; e += stride) {
    float val;
    if (e < 128) val = b2[e];
    else if (e < 256) val = b3[e - 128];
    else val = ((e & 15) < 4) ? b4[e & 3] : 0.f;  // only q==0 entries nonzero
    wb[e] = val;
  }
}

__launch_bounds__(256)
__global__ void nerf_main(const float* __restrict__ x, float* __restrict__ out,
                          const void* __restrict__ ws, int nGroups) {
  __shared__ __align__(16) unsigned short lds[39456];  // 78912 B

  {  // copy the whole constant slab: 78912/16 = 4932 16B chunks
    const u32x4* src = (const u32x4*)ws;
    u32x4* dst = (u32x4*)lds;
    for (int i = threadIdx.x; i < 4932; i += 256) dst[i] = src[i];
  }
  __syncthreads();

  const int lane = threadIdx.x & 63;
  const int wid = threadIdx.x >> 6;
  const int q = lane >> 4;
  const int n = lane & 15;

  const int waveId = blockIdx.x * 4 + wid;
  const int totalWaves = gridDim.x * 4;

  const unsigned short* lw = lds + lane * 8;              // frag f at + f*512
  const f32x4* bias2 = (const f32x4*)((const char*)lds + 77824) + q;  // + nt*4
  const f32x4* bias3 = (const f32x4*)((const char*)lds + 78336) + q;  // + nt*4
  const f32x4* b4p   = (const f32x4*)((const char*)lds + 78848) + q;

  const f32x4 zf = {0.f, 0.f, 0.f, 0.f};

  float px[2][6] = {};
  int g = waveId;
  if (g < nGroups && q == 0) {
#pragma unroll
    for (int t = 0; t < 2; ++t) {
      const float* p = x + (g * 32 + t * 16 + n) * 6;
      f32x2 a = *(const f32x2*)p, b = *(const f32x2*)(p + 2), c = *(const f32x2*)(p + 4);
      px[t][0] = a.x; px[t][1] = a.y; px[t][2] = b.x;
      px[t][3] = b.y; px[t][4] = c.x; px[t][5] = c.y;
    }
  }

  for (; g < nGroups; g += totalWaves) {
    // ---- x -> layer-1 B frags (q==0: k0..5 = x, k6 = 1.0 bias slot) ----
    short8 xb[2];
#pragma unroll
    for (int t = 0; t < 2; ++t) {
      short8 v = {0, 0, 0, 0, 0, 0, 0, 0};
      if (q == 0) {
        v[0] = (short)bfr(px[t][0]); v[1] = (short)bfr(px[t][1]);
        v[2] = (short)bfr(px[t][2]); v[3] = (short)bfr(px[t][3]);
        v[4] = (short)bfr(px[t][4]); v[5] = (short)bfr(px[t][5]);
        v[6] = (short)0x3F80;  // bf16 1.0
      }
      xb[t] = v;
    }
    const int gn = g + totalWaves;
    if (gn < nGroups && q == 0) {
#pragma unroll
      for (int t = 0; t < 2; ++t) {
        const float* p = x + (gn * 32 + t * 16 + n) * 6;
        f32x2 a = *(const f32x2*)p, b = *(const f32x2*)(p + 2), c = *(const f32x2*)(p + 4);
        px[t][0] = a.x; px[t][1] = a.y; px[t][2] = b.x;
        px[t][3] = b.y; px[t][4] = c.x; px[t][5] = c.y;
      }
    }

    short8 B1[2][4], B2[2][4];

    // ---- layer 1 (frags from LDS; bias in k-slot 6; C = 0) ----
#pragma unroll
    for (int ntp = 0; ntp < 4; ++ntp) {
      const short8 w0 = *(const short8*)(lw + (2 * ntp) * 512);
      const short8 w1 = *(const short8*)(lw + (2 * ntp + 1) * 512);
      f32x4 a0[2], a1[2];
#pragma unroll
      for (int t = 0; t < 2; ++t) {
        a0[t] = MFMA(w0, xb[t], zf);
        a1[t] = MFMA(w1, xb[t], zf);
      }
#pragma unroll
      for (int t = 0; t < 2; ++t) B1[t][ntp] = pack4(a0[t], a1[t]);
    }

    // ---- layer 2 (W2 frags 8..39; bias as C at ks==0) ----
#pragma unroll
    for (int ntp = 0; ntp < 4; ++ntp) {
      f32x4 a0[2], a1[2];
#pragma unroll
      for (int ks = 0; ks < 4; ++ks) {
        const short8 w0 = *(const short8*)(lw + (8 + ks * 8 + 2 * ntp) * 512);
        const short8 w1 = *(const short8*)(lw + (8 + ks * 8 + 2 * ntp + 1) * 512);
        if (ks == 0) {
          const f32x4 bv0 = bias2[(2 * ntp) * 4];
          const f32x4 bv1 = bias2[(2 * ntp + 1) * 4];
#pragma unroll
          for (int t = 0; t < 2; ++t) {
            a0[t] = MFMA(w0, B1[t][0], bv0);
            a1[t] = MFMA(w1, B1[t][0], bv1);
          }
        } else {
#pragma unroll
          for (int t = 0; t < 2; ++t) {
            a0[t] = MFMA(w0, B1[t][ks], a0[t]);
            a1[t] = MFMA(w1, B1[t][ks], a1[t]);
          }
        }
      }
#pragma unroll
      for (int t = 0; t < 2; ++t) B2[t][ntp] = pack4(a0[t], a1[t]);
    }

    // ---- layer 3 (W3 frags 40..71) ----
#pragma unroll
    for (int ntp = 0; ntp < 4; ++ntp) {
      f32x4 a0[2], a1[2];
#pragma unroll
      for (int ks = 0; ks < 4; ++ks) {
        const short8 w0 = *(const short8*)(lw + (40 + ks * 8 + 2 * ntp) * 512);
        const short8 w1 = *(const short8*)(lw + (40 + ks * 8 + 2 * ntp + 1) * 512);
        if (ks == 0) {
          const f32x4 bv0 = bias3[(2 * ntp) * 4];
          const f32x4 bv1 = bias3[(2 * ntp + 1) * 4];
#pragma unroll
          for (int t = 0; t < 2; ++t) {
            a0[t] = MFMA(w0, B2[t][0], bv0);
            a1[t] = MFMA(w1, B2[t][0], bv1);
          }
        } else {
#pragma unroll
          for (int t = 0; t < 2; ++t) {
            a0[t] = MFMA(w0, B2[t][ks], a0[t]);
            a1[t] = MFMA(w1, B2[t][ks], a1[t]);
          }
        }
      }
#pragma unroll
      for (int t = 0; t < 2; ++t) B1[t][ntp] = pack4(a0[t], a1[t]);  // reuse B1
    }

    // ---- layer 4 (frags 72..75; out rows at q==0) ----
    f32x4 o[2];
    {
      const f32x4 bv = b4p[0];
#pragma unroll
      for (int ks = 0; ks < 4; ++ks) {
        const short8 w = *(const short8*)(lw + (72 + ks) * 512);
        if (ks == 0) {
#pragma unroll
          for (int t = 0; t < 2; ++t) o[t] = MFMA(w, B1[t][0], bv);
        } else {
#pragma unroll
          for (int t = 0; t < 2; ++t) o[t] = MFMA(w, B1[t][ks], o[t]);
        }
      }
    }
    if (q == 0) {
#pragma unroll
      for (int t = 0; t < 2; ++t)
        *(f32x4*)(out + (g * 32 + t * 16 + n) * 4) = o[t];
    }
  }
}

extern "C" void kernel_launch(void* const* d_in, const int* in_sizes, int n_in,
                              void* d_out, int out_size, void* d_ws, size_t ws_size,
                              hipStream_t stream) {
  const float* x  = (const float*)d_in[0];
  const float* W1 = (const float*)d_in[1];
  const float* b1 = (const float*)d_in[2];
  const float* W2 = (const float*)d_in[3];
  const float* b2 = (const float*)d_in[4];
  const float* W3 = (const float*)d_in[5];
  const float* b3 = (const float*)d_in[6];
  const float* W4 = (const float*)d_in[7];
  const float* b4 = (const float*)d_in[8];
  float* out = (float*)d_out;

  const int N = in_sizes[0] / 6;
  const int nGroups = N / 32;  // 2 tiles of 16 rows per wave-iteration -> 32768

  nerf_stage<<<dim3(4), dim3(256), 0, stream>>>(W1, b1, W2, b2, W3, b3, W4, b4, d_ws);

  // 512 blocks = 2/CU (77 KB LDS each); 2048 waves x exactly 16 iterations
  nerf_main<<<dim3(512), dim3(256), 0, stream>>>(x, out, d_ws, nGroups);
}